// Round 4
// baseline (642.878 us; speedup 1.0000x reference)
//
#include <hip/hip_runtime.h>

#define NN 4096
#define CC 256
#define CQ 32    // C8
#define BB 4
#define MT 64    // m-tile of attn_fused
#define PLSTR 136
#define PLSZ (MT * PLSTR)

typedef _Float16 f16x8 __attribute__((ext_vector_type(8)));
typedef float    f32x4 __attribute__((ext_vector_type(4)));

// ---------------------------------------------------------------------------
// Kernel 1: fused QKV projection. 64 output rows per block so x is re-read
// only 5x (was 20x). W is wave-uniform -> scalar (SGPR) loads, no LDS.
// g==0: rows = Wq(32)+Wk(32); g=1..4: Wv rows (g-1)*64 .. +63.
// qT [b][n][32] f16, kT [b][m][32] f16, v [b][c][n] f16.
// ---------------------------------------------------------------------------
__global__ __launch_bounds__(128) void qkv_proj(
    const float* __restrict__ x,
    const float* __restrict__ Wq, const float* __restrict__ bq,
    const float* __restrict__ Wk, const float* __restrict__ bk,
    const float* __restrict__ Wv, const float* __restrict__ bv,
    _Float16* __restrict__ qT, _Float16* __restrict__ kT,
    _Float16* __restrict__ vf)
{
    const int t = threadIdx.x;
    const int g = blockIdx.y;            // 0..4
    const int b = blockIdx.z;
    const int n = blockIdx.x * 128 + t;

    const float *W0, *W1, *b0, *b1;
    if (g == 0) { W0 = Wq; W1 = Wk; b0 = bq; b1 = bk; }
    else {
        W0 = Wv + (size_t)(g - 1) * 64 * 256;
        W1 = W0 + 32 * 256;
        b0 = bv + (g - 1) * 64;
        b1 = b0 + 32;
    }

    float acc[64];
    #pragma unroll
    for (int r = 0; r < 32; ++r) { acc[r] = b0[r]; acc[32 + r] = b1[r]; }

    const float* xp = x + ((size_t)b * CC) * NN + n;
    for (int c = 0; c < CC; c += 4) {
        float xv0 = xp[(size_t)(c + 0) * NN];
        float xv1 = xp[(size_t)(c + 1) * NN];
        float xv2 = xp[(size_t)(c + 2) * NN];
        float xv3 = xp[(size_t)(c + 3) * NN];
        #pragma unroll
        for (int r = 0; r < 32; ++r)
            acc[r] += W0[r * 256 + c] * xv0 + W0[r * 256 + c + 1] * xv1
                    + W0[r * 256 + c + 2] * xv2 + W0[r * 256 + c + 3] * xv3;
        #pragma unroll
        for (int r = 0; r < 32; ++r)
            acc[32 + r] += W1[r * 256 + c] * xv0 + W1[r * 256 + c + 1] * xv1
                         + W1[r * 256 + c + 2] * xv2 + W1[r * 256 + c + 3] * xv3;
    }

    if (g == 0) {
        size_t base = ((size_t)b * NN + n) * CQ;
        #pragma unroll
        for (int j = 0; j < 4; ++j) {
            f16x8 hq, hk;
            #pragma unroll
            for (int r = 0; r < 8; ++r) {
                hq[r] = (_Float16)acc[j * 8 + r];
                hk[r] = (_Float16)acc[32 + j * 8 + r];
            }
            *(f16x8*)&qT[base + j * 8] = hq;
            *(f16x8*)&kT[base + j * 8] = hk;
        }
    } else {
        const int c0 = (g - 1) * 64;
        #pragma unroll
        for (int r = 0; r < 32; ++r) {
            vf[((size_t)b * CC + c0 + r) * NN + n]      = (_Float16)acc[r];
            vf[((size_t)b * CC + c0 + 32 + r) * NN + n] = (_Float16)acc[32 + r];
        }
    }
}

// ---------------------------------------------------------------------------
// Kernel 2: fully fused attention. MT=64 -> 256 blocks; 2 blocks/CU via
// __launch_bounds__(256,2). A / out written with NON-TEMPORAL stores so the
// 268 MB write stream does not evict the Q/V panels from L2. Pl is
// double-buffered -> ONE barrier per iteration, implemented as
// s_waitcnt lgkmcnt(0) + raw s_barrier so A-stores stay in flight.
// Frag layouts identical to the verified round-0 kernels.
// ---------------------------------------------------------------------------
__global__ __launch_bounds__(256, 2) void attn_fused(
    const _Float16* __restrict__ qT, const _Float16* __restrict__ kT,
    const _Float16* __restrict__ vf, const float* __restrict__ x,
    const float* __restrict__ gamma,
    float* __restrict__ A, float* __restrict__ out)
{
    __shared__ __align__(16) _Float16 Pl[2 * PLSZ];  // double-buffered [m][n]
    __shared__ float2 sred[4][MT];
    __shared__ float sM[MT], sR[MT];

    const int t  = threadIdx.x;
    const int l  = t & 63, w = t >> 6;
    const int lr = l & 15, lg = l >> 4;

    // bijective XCD swizzle (256 blocks, 8 XCDs -> 32 consecutive work/XCD)
    const int flat = blockIdx.y * (NN / MT) + blockIdx.x;
    const int work = (flat & 7) * (BB * NN / MT / 8) + (flat >> 3);
    const int b    = work / (NN / MT);
    const int m0   = (work % (NN / MT)) * MT;

    // persistent K fragments for this m-tile (A-op rows m = g*16 + lr)
    f16x8 kf[4];
    #pragma unroll
    for (int g = 0; g < 4; ++g)
        kf[g] = *(const f16x8*)&kT[((size_t)b * NN + m0 + g * 16 + lr) * CQ + lg * 8];

    const _Float16* qb = qT + (size_t)b * NN * CQ;

    // ---------------- pass A: stats ----------------
    float mx[4][4], sm[4][4];
    #pragma unroll
    for (int g = 0; g < 4; ++g)
        #pragma unroll
        for (int r = 0; r < 4; ++r) { mx[g][r] = -1e30f; sm[g][r] = 0.0f; }

    f16x8 qf[2];
    #pragma unroll
    for (int h = 0; h < 2; ++h)
        qf[h] = *(const f16x8*)&qb[(size_t)(w * 32 + h * 16 + lr) * CQ + lg * 8];

    for (int nt = 0; nt < NN / 128; ++nt) {
        const int ntn = (nt + 1) & (NN / 128 - 1);
        f16x8 qn[2];
        #pragma unroll
        for (int h = 0; h < 2; ++h)
            qn[h] = *(const f16x8*)&qb[(size_t)(ntn * 128 + w * 32 + h * 16 + lr) * CQ + lg * 8];

        #pragma unroll
        for (int g = 0; g < 4; ++g) {
            f32x4 s0 = (f32x4){0.f, 0.f, 0.f, 0.f};
            f32x4 s1 = (f32x4){0.f, 0.f, 0.f, 0.f};
            s0 = __builtin_amdgcn_mfma_f32_16x16x32_f16(kf[g], qf[0], s0, 0, 0, 0);
            s1 = __builtin_amdgcn_mfma_f32_16x16x32_f16(kf[g], qf[1], s1, 0, 0, 0);
            #pragma unroll
            for (int r = 0; r < 4; ++r) {
                float t0 = fmaxf(s0[r], s1[r]);
                float nm = fmaxf(mx[g][r], t0);
                float sadd = __expf(s0[r] - nm) + __expf(s1[r] - nm);
                sm[g][r] = sm[g][r] * __expf(mx[g][r] - nm) + sadd;
                mx[g][r] = nm;
            }
        }
        qf[0] = qn[0]; qf[1] = qn[1];
    }

    // reduce across the 16 lanes (l&15) sharing each m-row
    #pragma unroll
    for (int off = 1; off < 16; off <<= 1)
        #pragma unroll
        for (int g = 0; g < 4; ++g)
            #pragma unroll
            for (int r = 0; r < 4; ++r) {
                float pm = __shfl_xor(mx[g][r], off, 64);
                float ps = __shfl_xor(sm[g][r], off, 64);
                float nm = fmaxf(mx[g][r], pm);
                sm[g][r] = sm[g][r] * __expf(mx[g][r] - nm) + ps * __expf(pm - nm);
                mx[g][r] = nm;
            }

    if (lr == 0) {
        #pragma unroll
        for (int g = 0; g < 4; ++g)
            #pragma unroll
            for (int r = 0; r < 4; ++r)
                sred[w][g * 16 + lg * 4 + r] = make_float2(mx[g][r], sm[g][r]);
    }
    __syncthreads();
    if (t < MT) {
        float2 a0 = sred[0][t], a1 = sred[1][t], a2 = sred[2][t], a3 = sred[3][t];
        float M = fmaxf(fmaxf(a0.x, a1.x), fmaxf(a2.x, a3.x));
        float S = a0.y * __expf(a0.x - M) + a1.y * __expf(a1.x - M)
                + a2.y * __expf(a2.x - M) + a3.y * __expf(a3.x - M);
        sM[t] = M; sR[t] = 1.0f / S;
    }
    __syncthreads();

    // ---------------- pass B: write A + accumulate o ----------------
    f32x4 acc[4][4];   // o rows c = w*64 + g*16 + lg*4 + r ; cols m = h*16 + lr
    #pragma unroll
    for (int g = 0; g < 4; ++g)
        #pragma unroll
        for (int h = 0; h < 4; ++h)
            acc[g][h] = (f32x4){0.f, 0.f, 0.f, 0.f};

    const _Float16* vb = vf + ((size_t)b * CC + w * 64) * NN;
    float* Ab = A + ((size_t)b * NN + m0) * NN;

    #pragma unroll
    for (int h = 0; h < 2; ++h)
        qf[h] = *(const f16x8*)&qb[(size_t)(w * 32 + h * 16 + lr) * CQ + lg * 8];

    #pragma unroll 2
    for (int nt = 0; nt < NN / 128; ++nt) {
        _Float16* Plb = &Pl[(nt & 1) * PLSZ];

        // QK^T + normalize; scatter to A (non-temporal) and Pl (f16)
        #pragma unroll
        for (int g = 0; g < 4; ++g) {
            f32x4 s0 = (f32x4){0.f, 0.f, 0.f, 0.f};
            f32x4 s1 = (f32x4){0.f, 0.f, 0.f, 0.f};
            s0 = __builtin_amdgcn_mfma_f32_16x16x32_f16(kf[g], qf[0], s0, 0, 0, 0);
            s1 = __builtin_amdgcn_mfma_f32_16x16x32_f16(kf[g], qf[1], s1, 0, 0, 0);
            f32x4 Mv = *(const f32x4*)&sM[g * 16 + lg * 4];
            f32x4 Rv = *(const f32x4*)&sR[g * 16 + lg * 4];
            #pragma unroll
            for (int r = 0; r < 4; ++r) {
                float p0 = __expf(s0[r] - Mv[r]) * Rv[r];
                float p1 = __expf(s1[r] - Mv[r]) * Rv[r];
                int m   = g * 16 + lg * 4 + r;
                int nc0 = w * 32 + lr, nc1 = nc0 + 16;
                __builtin_nontemporal_store(p0, &Ab[(size_t)m * NN + nt * 128 + nc0]);
                __builtin_nontemporal_store(p1, &Ab[(size_t)m * NN + nt * 128 + nc1]);
                Plb[m * PLSTR + nc0] = (_Float16)p0;
                Plb[m * PLSTR + nc1] = (_Float16)p1;
            }
        }

        // prefetch next Q fragments (stay in flight across the barrier)
        const int ntn = (nt + 1) & (NN / 128 - 1);
        f16x8 qn0 = *(const f16x8*)&qb[(size_t)(ntn * 128 + w * 32 + lr) * CQ + lg * 8];
        f16x8 qn1 = *(const f16x8*)&qb[(size_t)(ntn * 128 + w * 32 + 16 + lr) * CQ + lg * 8];

        // publish Pl: wait LDS only -- A-stores/Q-prefetch NOT drained
        asm volatile("s_waitcnt lgkmcnt(0)" ::: "memory");
        __builtin_amdgcn_s_barrier();

        // PV: o[c][m] += v[c][n] * P[m][n], k = n (128 per tile, 4 slices)
        #pragma unroll
        for (int ks = 0; ks < 4; ++ks) {
            f16x8 vfr[4], pfr[4];
            #pragma unroll
            for (int g = 0; g < 4; ++g)
                vfr[g] = *(const f16x8*)&vb[(size_t)(g * 16 + lr) * NN + nt * 128 + ks * 32 + lg * 8];
            #pragma unroll
            for (int h = 0; h < 4; ++h)
                pfr[h] = *(const f16x8*)&Plb[(h * 16 + lr) * PLSTR + ks * 32 + lg * 8];
            #pragma unroll
            for (int g = 0; g < 4; ++g)
                #pragma unroll
                for (int h = 0; h < 4; ++h)
                    acc[g][h] = __builtin_amdgcn_mfma_f32_16x16x32_f16(
                        vfr[g], pfr[h], acc[g][h], 0, 0, 0);
        }
        qf[0] = qn0; qf[1] = qn1;
    }

    // epilogue: out = x + gamma*o (non-temporal; out is never re-read)
    const float gm = gamma[0];
    #pragma unroll
    for (int g = 0; g < 4; ++g) {
        #pragma unroll
        for (int r = 0; r < 4; ++r) {
            int c = w * 64 + g * 16 + lg * 4 + r;
            size_t ro = ((size_t)b * CC + c) * NN + m0;
            #pragma unroll
            for (int h = 0; h < 4; ++h) {
                int m = h * 16 + lr;
                __builtin_nontemporal_store(x[ro + m] + gm * acc[g][h][r], &out[ro + m]);
            }
        }
    }
}

// ---------------------------------------------------------------------------
extern "C" void kernel_launch(void* const* d_in, const int* in_sizes, int n_in,
                              void* d_out, int out_size, void* d_ws, size_t ws_size,
                              hipStream_t stream) {
    const float* x     = (const float*)d_in[0];
    const float* Wq    = (const float*)d_in[1];
    const float* bq    = (const float*)d_in[2];
    const float* Wk    = (const float*)d_in[3];
    const float* bk    = (const float*)d_in[4];
    const float* Wv    = (const float*)d_in[5];
    const float* bv    = (const float*)d_in[6];
    const float* gamma = (const float*)d_in[7];

    float* out = (float*)d_out;                       // [B, C, H, W]
    float* A   = out + (size_t)BB * CC * NN;          // [B, N, N] attention_map

    _Float16* qT = (_Float16*)d_ws;                   // [B, N, 32]
    _Float16* kT = qT + (size_t)BB * NN * CQ;         // [B, N, 32]
    _Float16* vf = kT + (size_t)BB * NN * CQ;         // [B, C, N]

    qkv_proj  <<<dim3(NN / 128, 5, BB), 128, 0, stream>>>(x, Wq, bq, Wk, bk, Wv, bv, qT, kT, vf);
    attn_fused<<<dim3(NN / MT, BB),     256, 0, stream>>>(qT, kT, vf, x, gamma, A, out);
}